// Round 7
// baseline (1304.433 us; speedup 1.0000x reference)
//
#include <hip/hip_runtime.h>
#include <hip/hip_bf16.h>

#define SEQ 4096
#define DIM 256
#define BATCH 4
#define LAYERS 4
#define QT (SEQ / 16)        // 256 q-tiles per batch
#define PB (BATCH * QT)      // 1024 q-tiles total
#define KVB 32               // keys per KV step

typedef __attribute__((ext_vector_type(8))) short bf16x8;
typedef __attribute__((ext_vector_type(4))) float f32x4;

__device__ __forceinline__ unsigned short f2bf(float f) {
    union { float f; unsigned u; } v; v.f = f;
    unsigned r = v.u + 0x7fff + ((v.u >> 16) & 1);   // round-to-nearest-even
    return (unsigned short)(r >> 16);
}

__device__ __forceinline__ float bf2f(unsigned short h) {
    union { unsigned u; float f; } v; v.u = ((unsigned)h) << 16;
    return v.f;
}

__device__ __forceinline__ unsigned cvt_pk_bf16(float lo, float hi) {
    unsigned r;
    asm volatile("v_cvt_pk_bf16_f32 %0, %1, %2" : "=v"(r) : "v"(lo), "v"(hi));
    return r;
}

__device__ __forceinline__ float bperm_f(float v, int srclane) {
    return __int_as_float(__builtin_amdgcn_ds_bpermute(srclane << 2, __float_as_int(v)));
}

// async global->LDS, 16B per lane; LDS dest = wave-uniform base + lane*16
__device__ __forceinline__ void gload_lds16(const void* g, void* l) {
    __builtin_amdgcn_global_load_lds(
        (const __attribute__((address_space(1))) unsigned int*)g,
        (__attribute__((address_space(3))) unsigned int*)l, 16, 0, 0);
}

// ---------------- fp32 -> bf16 conversion (vectorized) ----------------
__global__ __launch_bounds__(256) void cvt_kernel(const float* __restrict__ in,
                                                  unsigned short* __restrict__ out,
                                                  int n) {
    int i = (blockIdx.x * blockDim.x + threadIdx.x) * 4;
    if (i + 3 < n) {
        float4 v = *(const float4*)(in + i);
        ushort4 o = {f2bf(v.x), f2bf(v.y), f2bf(v.z), f2bf(v.w)};
        *(ushort4*)(out + i) = o;
    }
}

// ---------------- fused QKV projection (no LDS, W direct from L2, packed stores) ----
// q/k: swapped MFMA (A=W,B=x) -> thread owns 4 consecutive out-cols -> ushort4 row store.
// v:   normal MFMA -> thread owns 4 consecutive rows -> ushort4 store into transposed vt.
// q is pre-scaled by (1/sqrt(D))*log2(e) so attention skips per-step score scaling.
__global__ __launch_bounds__(256) void projqkv_kernel(const unsigned short* __restrict__ xb,
                                                      const unsigned short* __restrict__ Wq,
                                                      const unsigned short* __restrict__ Wk,
                                                      const unsigned short* __restrict__ Wv,
                                                      const float* __restrict__ bq,
                                                      const float* __restrict__ bk,
                                                      const float* __restrict__ bv,
                                                      unsigned short* __restrict__ outq,
                                                      unsigned short* __restrict__ outk,
                                                      unsigned short* __restrict__ outv) {
    int lane = threadIdx.x & 63, wid = threadIdx.x >> 6;
    int c = lane & 15, g = lane >> 4;
    int m0 = blockIdx.x * 64 + wid * 16;
    int n0 = blockIdx.y * 64;

    bf16x8 xa[8];
    const unsigned short* xrow = xb + (size_t)(m0 + c) * DIM + g * 8;
    #pragma unroll
    for (int s = 0; s < 8; ++s) xa[s] = *(const bf16x8*)(xrow + s * 32);

    const float KQ = 0.09016844f;   // (1/16) * log2(e)

    #pragma unroll
    for (int z = 0; z < 2; ++z) {
        const unsigned short* Wb = z ? Wk : Wq;
        const float* bias        = z ? bk : bq;
        unsigned short* out      = z ? outk : outq;
        float scale = z ? 1.0f : KQ;

        f32x4 acc[4] = {};
        __builtin_amdgcn_s_setprio(1);
        #pragma unroll
        for (int s = 0; s < 8; ++s) {
            #pragma unroll
            for (int nt = 0; nt < 4; ++nt) {
                bf16x8 wf = *(const bf16x8*)(Wb + (size_t)(n0 + nt * 16 + c) * DIM + s * 32 + g * 8);
                acc[nt] = __builtin_amdgcn_mfma_f32_16x16x32_bf16(wf, xa[s], acc[nt], 0, 0, 0);
            }
        }
        __builtin_amdgcn_s_setprio(0);

        #pragma unroll
        for (int nt = 0; nt < 4; ++nt) {
            int col0 = n0 + nt * 16 + g * 4;
            float4 b4 = *(const float4*)(bias + col0);
            ushort4 h = {f2bf((acc[nt][0] + b4.x) * scale),
                         f2bf((acc[nt][1] + b4.y) * scale),
                         f2bf((acc[nt][2] + b4.z) * scale),
                         f2bf((acc[nt][3] + b4.w) * scale)};
            *(ushort4*)(out + (size_t)(m0 + c) * DIM + col0) = h;
        }
    }

    {   // V
        f32x4 acc[4] = {};
        __builtin_amdgcn_s_setprio(1);
        #pragma unroll
        for (int s = 0; s < 8; ++s) {
            #pragma unroll
            for (int nt = 0; nt < 4; ++nt) {
                bf16x8 wf = *(const bf16x8*)(Wv + (size_t)(n0 + nt * 16 + c) * DIM + s * 32 + g * 8);
                acc[nt] = __builtin_amdgcn_mfma_f32_16x16x32_bf16(xa[s], wf, acc[nt], 0, 0, 0);
            }
        }
        __builtin_amdgcn_s_setprio(0);

        int b    = m0 >> 12;
        int sidx = (m0 & (SEQ - 1)) + g * 4;
        #pragma unroll
        for (int nt = 0; nt < 4; ++nt) {
            int col = n0 + nt * 16 + c;
            float bv_ = bv[col];
            ushort4 h = {f2bf(acc[nt][0] + bv_), f2bf(acc[nt][1] + bv_),
                         f2bf(acc[nt][2] + bv_), f2bf(acc[nt][3] + bv_)};
            *(ushort4*)(outv + (((size_t)(b * DIM + col)) << 12) + sidx) = h;
        }
    }
}

// ---------------- causal flash attention ----------------
// K+V staged in LDS, SINGLE-buffered (36.9 KB -> 4 blocks/CU); cross-block TLP
// hides the per-step stage latency. Swapped QK^T -> lane-local softmax.
// Grid: 256*split blocks, LPT (long quads first) + XCD/batch pinning.
__global__ __launch_bounds__(256, 4) void attn_kernel(const unsigned short* __restrict__ qb,
                                                      const unsigned short* __restrict__ kb,
                                                      const unsigned short* __restrict__ vt,
                                                      const float* __restrict__ xres,
                                                      float* __restrict__ xout,
                                                      unsigned short* __restrict__ xb_next,
                                                      unsigned short* __restrict__ partO,
                                                      float* __restrict__ partM,
                                                      float* __restrict__ partL,
                                                      int split) {
    __shared__ unsigned short Klds[32 * 256];   // 16 KB, XOR-swizzled rows
    __shared__ unsigned short Vlds[32 * 256];   // 16 KB, chunk-major
    __shared__ unsigned int   Plds[4][256];     // 4 KB per-wave P patch

    int tid  = threadIdx.x;
    int lane = tid & 63, wid = tid >> 6;
    int c = lane & 15, g = lane >> 4;

    // decode: XCD pair (d&7) serves batch (d&7)>>1; quads descend (LPT)
    int d  = blockIdx.x;
    int b  = (d & 7) >> 1;
    int ls = __popc(split - 1);
    int combo = (d & 1) | ((d >> 3) << 1);
    int quad  = 63 - (combo >> ls);
    int s_idx = combo & (split - 1);

    int qtile = quad * 4 + wid;
    int q0 = qtile * 16;
    int nsteps_own = (q0 + 47) >> 5;
    int nsteps_max = (quad * 64 + 95) >> 5;
    int cnt_own = (nsteps_own > s_idx) ? (nsteps_own - s_idx + split - 1) / split : 0;
    int cnt_max = (nsteps_max > s_idx) ? (nsteps_max - s_idx + split - 1) / split : 0;

    const unsigned short* kbase = kb + (size_t)b * SEQ * DIM;
    const unsigned short* vbase = vt + (size_t)b * DIM * SEQ;

    auto STAGE = [&](int k0) {
        #pragma unroll
        for (int r = 0; r < 4; ++r) {
            // K: LDS byte L = r*4096 + tid*16 -> row k = r*8 + tid/32, slot sl = tid&31
            int k  = r * 8 + (tid >> 5);
            int sl = tid & 31;
            const unsigned short* ks = kbase + (size_t)(k0 + k) * DIM + ((sl ^ (k & 7)) << 3);
            gload_lds16(ks, (char*)&Klds[0] + r * 4096 + wid * 1024);
            // V: LDS byte L = r*4096 + tid*16 -> ch = r, d = tid
            const unsigned short* vs = vbase + (size_t)tid * SEQ + k0 + r * 8;
            gload_lds16(vs, (char*)&Vlds[0] + r * 4096 + wid * 1024);
        }
    };

    // hoist Q fragments (q already pre-scaled by (1/sqrt(D))*log2e)
    bf16x8 qf[8];
    const unsigned short* qp = qb + ((size_t)(b * SEQ + q0 + c)) * DIM + g * 8;
    #pragma unroll
    for (int s = 0; s < 8; ++s) qf[s] = *(const bf16x8*)(qp + s * 32);

    f32x4 o[16] = {};
    float m_run = -1e30f, l_run = 0.f;    // per-lane scalars, q = q0 + c
    int xs = ((c >> 1) & 3) << 2;         // P-patch slot rotation

    if (cnt_max > 0) {
        STAGE(s_idx * KVB);

        for (int j = 0; j < cnt_max; ++j) {
            __syncthreads();   // stage loads drained (vmcnt0) + all waves arrived

            if (j < cnt_own) {
                int k0 = (s_idx + j * split) * KVB;

                // ---- swapped QK^T, two 4-deep chains per t (halved dep latency) ----
                f32x4 sa[2][2] = {};
                const unsigned short* Kb = &Klds[0];
                __builtin_amdgcn_s_setprio(1);
                #pragma unroll
                for (int t = 0; t < 2; ++t) {
                    int krow = t * 16 + c;
                    #pragma unroll
                    for (int s = 0; s < 8; ++s) {
                        int off = krow * 256 + (((s * 4 + g) ^ (c & 7)) << 3);
                        bf16x8 kf = *(const bf16x8*)(Kb + off);
                        sa[t][s >> 2] = __builtin_amdgcn_mfma_f32_16x16x32_bf16(kf, qf[s], sa[t][s >> 2], 0, 0, 0);
                    }
                }
                __builtin_amdgcn_s_setprio(0);

                // ---- mask (edge steps only, wave-uniform branch) + row max ----
                float sv[2][4];
                float mloc = -1e30f;
                if (k0 + (KVB - 1) <= q0) {
                    #pragma unroll
                    for (int t = 0; t < 2; ++t)
                        #pragma unroll
                        for (int i = 0; i < 4; ++i) {
                            sv[t][i] = sa[t][0][i] + sa[t][1][i];
                            mloc = fmaxf(mloc, sv[t][i]);
                        }
                } else {
                    int qv = q0 + c;
                    #pragma unroll
                    for (int t = 0; t < 2; ++t)
                        #pragma unroll
                        for (int i = 0; i < 4; ++i) {
                            int key = k0 + t * 16 + g * 4 + i;
                            sv[t][i] = (key <= qv) ? (sa[t][0][i] + sa[t][1][i]) : -1e30f;
                            mloc = fmaxf(mloc, sv[t][i]);
                        }
                }
                mloc = fmaxf(mloc, __shfl_xor(mloc, 16));
                mloc = fmaxf(mloc, __shfl_xor(mloc, 32));

                // ---- defer-rescale (THR=8 in exp2 domain) ----
                if (!__all(mloc <= m_run + 8.0f)) {
                    float mnew = fmaxf(m_run, mloc);
                    float corr = exp2f(m_run - mnew);
                    m_run = mnew;
                    l_run *= corr;
                    #pragma unroll
                    for (int i = 0; i < 4; ++i) {
                        float cr = bperm_f(corr, g * 4 + i);
                        #pragma unroll
                        for (int dt = 0; dt < 16; ++dt) o[dt][i] *= cr;
                    }
                }

                // ---- P = exp2(S-m); pack to 2-way-free swizzled patch ----
                #pragma unroll
                for (int t = 0; t < 2; ++t) {
                    float p0 = exp2f(sv[t][0] - m_run);
                    float p1 = exp2f(sv[t][1] - m_run);
                    float p2 = exp2f(sv[t][2] - m_run);
                    float p3 = exp2f(sv[t][3] - m_run);
                    l_run += (p0 + p1) + (p2 + p3);
                    unsigned w0 = cvt_pk_bf16(p0, p1);
                    unsigned w1 = cvt_pk_bf16(p2, p3);
                    int s0 = (t * 8 + g * 2 + xs) & 15;    // slot(pair) = (pair+xs)&15
                    Plds[wid][c * 16 + s0]     = w0;
                    Plds[wid][c * 16 + s0 + 1] = w1;
                }
                bf16x8 paf = *(const bf16x8*)&Plds[wid][c * 16 + ((g * 4 + xs) & 15)];

                // ---- O += P V from LDS ----
                const unsigned short* Vb = &Vlds[0];
                __builtin_amdgcn_s_setprio(1);
                #pragma unroll
                for (int dt = 0; dt < 16; ++dt) {
                    bf16x8 vf = *(const bf16x8*)(Vb + g * 2048 + (dt * 16 + c) * 8);
                    o[dt] = __builtin_amdgcn_mfma_f32_16x16x32_bf16(paf, vf, o[dt], 0, 0, 0);
                }
                __builtin_amdgcn_s_setprio(0);
            }

            __syncthreads();   // all waves done reading buffer
            if (j + 1 < cnt_max) STAGE((s_idx + (j + 1) * split) * KVB);
        }
    }

    // ---- epilogue: reduce per-lane l partials across g-groups ----
    float lfull = l_run;
    lfull += __shfl_xor(lfull, 16);
    lfull += __shfl_xor(lfull, 32);

    if (split == 1) {
        float invl = 1.0f / lfull;
        float invr[4];
        #pragma unroll
        for (int i = 0; i < 4; ++i) invr[i] = bperm_f(invl, g * 4 + i);
        #pragma unroll
        for (int i = 0; i < 4; ++i) {
            int row = q0 + g * 4 + i;
            #pragma unroll
            for (int dt = 0; dt < 16; ++dt) {
                int col = dt * 16 + c;
                size_t idx = ((size_t)b * SEQ + row) * DIM + col;
                float r = o[dt][i] * invr[i] + xres[idx];
                xout[idx] = r;
                xb_next[idx] = f2bf(r);
            }
        }
    } else {
        int gq = b * QT + qtile;
        size_t pbase = ((size_t)(s_idx * PB + gq)) * 16;
        if (g == 0) {
            partM[pbase + c] = m_run;
            partL[pbase + c] = lfull;
        }
        #pragma unroll
        for (int i = 0; i < 4; ++i) {
            int row_r = g * 4 + i;
            #pragma unroll
            for (int dt = 0; dt < 16; ++dt) {
                partO[(pbase + row_r) * DIM + dt * 16 + c] = f2bf(o[dt][i]);
            }
        }
    }
}

// ---------------- split-KV combine + residual (partO in bf16) ----------------
__global__ __launch_bounds__(256) void combine_kernel(const unsigned short* __restrict__ partO,
                                                      const float* __restrict__ partM,
                                                      const float* __restrict__ partL,
                                                      const float* __restrict__ xres,
                                                      float* __restrict__ xout,
                                                      unsigned short* __restrict__ xb_next,
                                                      int split) {
    int q = blockIdx.x, b = blockIdx.y;
    int gq = b * QT + q;
    int t = threadIdx.x;
    int row = t >> 4, ci = t & 15;

    float mv[4];
    float M = -1e30f;
    for (int s = 0; s < split; ++s) {
        mv[s] = partM[((size_t)(s * PB + gq)) * 16 + row];
        M = fmaxf(M, mv[s]);
    }
    float L = 0.f;
    for (int s = 0; s < split; ++s)
        L += partL[((size_t)(s * PB + gq)) * 16 + row] * exp2f(mv[s] - M);
    float invL = 1.0f / L;

    float acc[16] = {};
    for (int s = 0; s < split; ++s) {
        float w = exp2f(mv[s] - M);
        if (w > 0.f) {
            const unsigned short* po = partO + (((size_t)(s * PB + gq)) * 16 + row) * DIM + ci * 16;
            #pragma unroll
            for (int j = 0; j < 4; ++j) {
                ushort4 v = *(const ushort4*)(po + j * 4);
                acc[j * 4 + 0] += w * bf2f(v.x);
                acc[j * 4 + 1] += w * bf2f(v.y);
                acc[j * 4 + 2] += w * bf2f(v.z);
                acc[j * 4 + 3] += w * bf2f(v.w);
            }
        }
    }

    size_t base = ((size_t)(b * SEQ + q * 16 + row)) * DIM + ci * 16;
    #pragma unroll
    for (int j = 0; j < 4; ++j) {
        float4 r = *(const float4*)(xres + base + j * 4);
        float4 ov;
        ov.x = acc[j * 4 + 0] * invL + r.x;
        ov.y = acc[j * 4 + 1] * invL + r.y;
        ov.z = acc[j * 4 + 2] * invL + r.z;
        ov.w = acc[j * 4 + 3] * invL + r.w;
        *(float4*)(xout + base + j * 4) = ov;
        ushort4 hb = {f2bf(ov.x), f2bf(ov.y), f2bf(ov.z), f2bf(ov.w)};
        *(ushort4*)(xb_next + base + j * 4) = hb;
    }
}

// ---------------- launch ----------------
extern "C" void kernel_launch(void* const* d_in, const int* in_sizes, int n_in,
                              void* d_out, int out_size, void* d_ws, size_t ws_size,
                              hipStream_t stream) {
    const float* x_in = (const float*)d_in[0];
    const float* Wq   = (const float*)d_in[1];
    const float* bq   = (const float*)d_in[2];
    const float* Wk   = (const float*)d_in[3];
    const float* bk   = (const float*)d_in[4];
    const float* Wv   = (const float*)d_in[5];
    const float* bv   = (const float*)d_in[6];
    float* xout = (float*)d_out;

    const size_t SD = (size_t)BATCH * SEQ * DIM;
    const size_t WL = (size_t)LAYERS * DIM * DIM;
    unsigned short* qb  = (unsigned short*)d_ws;
    unsigned short* kbf = qb  + SD;
    unsigned short* vt  = kbf + SD;
    unsigned short* xb  = vt  + SD;
    unsigned short* Wqb = xb  + SD;
    unsigned short* Wkb = Wqb + WL;
    unsigned short* Wvb = Wkb + WL;
    size_t base_bytes = (4 * SD + 3 * WL) * sizeof(unsigned short);   // ~35.1 MB

    int split = 1;
    for (int s = 4; s >= 2; s >>= 1) {
        size_t need = base_bytes + (size_t)s * PB * 16 * (DIM + 2) * sizeof(float);
        if (ws_size >= need) { split = s; break; }
    }
    unsigned short* partO = (unsigned short*)((char*)d_ws + base_bytes);
    float* partM = (float*)(partO + (size_t)split * PB * 16 * DIM);
    float* partL = partM + (size_t)split * PB * 16;

    {
        int n = (int)WL;
        int blocks = (n / 4 + 255) / 256;
        cvt_kernel<<<blocks, 256, 0, stream>>>(Wq, Wqb, n);
        cvt_kernel<<<blocks, 256, 0, stream>>>(Wk, Wkb, n);
        cvt_kernel<<<blocks, 256, 0, stream>>>(Wv, Wvb, n);
    }
    {
        int n = (int)SD;
        int blocks = (n / 4 + 255) / 256;
        cvt_kernel<<<blocks, 256, 0, stream>>>(x_in, xb, n);
    }

    dim3 pgrid(BATCH * SEQ / 64, DIM / 64), pblk(256);
    dim3 agrid(256 * split), ablk(256);
    dim3 cgrid(QT, BATCH), cblk(256);

    for (int l = 0; l < LAYERS; ++l) {
        const float* xcur = (l == 0) ? x_in : xout;
        size_t wl_off = (size_t)l * DIM * DIM;
        projqkv_kernel<<<pgrid, pblk, 0, stream>>>(xb, Wqb + wl_off, Wkb + wl_off, Wvb + wl_off,
                                                   bq + l * DIM, bk + l * DIM, bv + l * DIM,
                                                   qb, kbf, vt);
        attn_kernel<<<agrid, ablk, 0, stream>>>(qb, kbf, vt, xcur, xout, xb,
                                                partO, partM, partL, split);
        if (split > 1)
            combine_kernel<<<cgrid, cblk, 0, stream>>>(partO, partM, partL, xcur, xout, xb, split);
    }
}

// Round 10
// 662.187 us; speedup vs baseline: 1.9699x; 1.9699x over previous
//
#include <hip/hip_runtime.h>
#include <hip/hip_bf16.h>

#define SEQ 4096
#define DIM 256
#define BATCH 4
#define LAYERS 4
#define QT (SEQ / 16)        // 256 q-tiles per batch
#define PB (BATCH * QT)      // 1024 q-tiles total
#define KVB 32               // keys per KV step

typedef __attribute__((ext_vector_type(8))) short bf16x8;
typedef __attribute__((ext_vector_type(4))) float f32x4;

__device__ __forceinline__ unsigned short f2bf(float f) {
    union { float f; unsigned u; } v; v.f = f;
    unsigned r = v.u + 0x7fff + ((v.u >> 16) & 1);   // round-to-nearest-even
    return (unsigned short)(r >> 16);
}

__device__ __forceinline__ float bf2f(unsigned short h) {
    union { unsigned u; float f; } v; v.u = ((unsigned)h) << 16;
    return v.f;
}

__device__ __forceinline__ unsigned cvt_pk_bf16(float lo, float hi) {
    unsigned r;
    asm volatile("v_cvt_pk_bf16_f32 %0, %1, %2" : "=v"(r) : "v"(lo), "v"(hi));
    return r;
}

__device__ __forceinline__ float bperm_f(float v, int srclane) {
    return __int_as_float(__builtin_amdgcn_ds_bpermute(srclane << 2, __float_as_int(v)));
}

// async global->LDS, 16B per lane; LDS dest = wave-uniform base + lane*16
__device__ __forceinline__ void gload_lds16(const void* g, void* l) {
    __builtin_amdgcn_global_load_lds(
        (const __attribute__((address_space(1))) unsigned int*)g,
        (__attribute__((address_space(3))) unsigned int*)l, 16, 0, 0);
}

// ---------------- fp32 -> bf16 conversion (vectorized) ----------------
__global__ __launch_bounds__(256) void cvt_kernel(const float* __restrict__ in,
                                                  unsigned short* __restrict__ out,
                                                  int n) {
    int i = (blockIdx.x * blockDim.x + threadIdx.x) * 4;
    if (i + 3 < n) {
        float4 v = *(const float4*)(in + i);
        ushort4 o = {f2bf(v.x), f2bf(v.y), f2bf(v.z), f2bf(v.w)};
        *(ushort4*)(out + i) = o;
    }
}

// ---------------- fused QKV projection (no LDS, W direct from L2, packed stores) ----
// q/k: swapped MFMA (A=W,B=x) -> thread owns 4 consecutive out-cols -> ushort4 row store.
// v:   normal MFMA -> thread owns 4 consecutive rows -> ushort4 store into transposed vt.
// q is pre-scaled by (1/sqrt(D))*log2(e) so attention skips per-step score scaling.
__global__ __launch_bounds__(256) void projqkv_kernel(const unsigned short* __restrict__ xb,
                                                      const unsigned short* __restrict__ Wq,
                                                      const unsigned short* __restrict__ Wk,
                                                      const unsigned short* __restrict__ Wv,
                                                      const float* __restrict__ bq,
                                                      const float* __restrict__ bk,
                                                      const float* __restrict__ bv,
                                                      unsigned short* __restrict__ outq,
                                                      unsigned short* __restrict__ outk,
                                                      unsigned short* __restrict__ outv) {
    int lane = threadIdx.x & 63, wid = threadIdx.x >> 6;
    int c = lane & 15, g = lane >> 4;
    int m0 = blockIdx.x * 64 + wid * 16;
    int n0 = blockIdx.y * 64;

    bf16x8 xa[8];
    const unsigned short* xrow = xb + (size_t)(m0 + c) * DIM + g * 8;
    #pragma unroll
    for (int s = 0; s < 8; ++s) xa[s] = *(const bf16x8*)(xrow + s * 32);

    const float KQ = 0.09016844f;   // (1/16) * log2(e)

    #pragma unroll
    for (int z = 0; z < 2; ++z) {
        const unsigned short* Wb = z ? Wk : Wq;
        const float* bias        = z ? bk : bq;
        unsigned short* out      = z ? outk : outq;
        float scale = z ? 1.0f : KQ;

        f32x4 acc[4] = {};
        __builtin_amdgcn_s_setprio(1);
        #pragma unroll
        for (int s = 0; s < 8; ++s) {
            #pragma unroll
            for (int nt = 0; nt < 4; ++nt) {
                bf16x8 wf = *(const bf16x8*)(Wb + (size_t)(n0 + nt * 16 + c) * DIM + s * 32 + g * 8);
                acc[nt] = __builtin_amdgcn_mfma_f32_16x16x32_bf16(wf, xa[s], acc[nt], 0, 0, 0);
            }
        }
        __builtin_amdgcn_s_setprio(0);

        #pragma unroll
        for (int nt = 0; nt < 4; ++nt) {
            int col0 = n0 + nt * 16 + g * 4;
            float4 b4 = *(const float4*)(bias + col0);
            ushort4 h = {f2bf((acc[nt][0] + b4.x) * scale),
                         f2bf((acc[nt][1] + b4.y) * scale),
                         f2bf((acc[nt][2] + b4.z) * scale),
                         f2bf((acc[nt][3] + b4.w) * scale)};
            *(ushort4*)(out + (size_t)(m0 + c) * DIM + col0) = h;
        }
    }

    {   // V
        f32x4 acc[4] = {};
        __builtin_amdgcn_s_setprio(1);
        #pragma unroll
        for (int s = 0; s < 8; ++s) {
            #pragma unroll
            for (int nt = 0; nt < 4; ++nt) {
                bf16x8 wf = *(const bf16x8*)(Wv + (size_t)(n0 + nt * 16 + c) * DIM + s * 32 + g * 8);
                acc[nt] = __builtin_amdgcn_mfma_f32_16x16x32_bf16(xa[s], wf, acc[nt], 0, 0, 0);
            }
        }
        __builtin_amdgcn_s_setprio(0);

        int b    = m0 >> 12;
        int sidx = (m0 & (SEQ - 1)) + g * 4;
        #pragma unroll
        for (int nt = 0; nt < 4; ++nt) {
            int col = n0 + nt * 16 + c;
            float bv_ = bv[col];
            ushort4 h = {f2bf(acc[nt][0] + bv_), f2bf(acc[nt][1] + bv_),
                         f2bf(acc[nt][2] + bv_), f2bf(acc[nt][3] + bv_)};
            *(ushort4*)(outv + (((size_t)(b * DIM + col)) << 12) + sidx) = h;
        }
    }
}

// ---------------- causal flash attention ----------------
// K double-buffered (32KB) + V single-buffered (16KB) + P (4KB) = 52.9KB
// -> 3 blocks/CU. Per step: full barrier -> stage V(j)+K(j+1) -> QK+softmax ->
// {per-wave counted vmcnt + RAW s_barrier} (cross-wave V visibility; K(j+1)
// stays in flight) -> PV. The raw barrier is the fix for r8's race: vmcnt is
// per-wave, V is cross-wave, so every wave must drain its own V loads and
// arrive before any wave reads V.
__global__ __launch_bounds__(256, 3) void attn_kernel(const unsigned short* __restrict__ qb,
                                                      const unsigned short* __restrict__ kb,
                                                      const unsigned short* __restrict__ vt,
                                                      const float* __restrict__ xres,
                                                      float* __restrict__ xout,
                                                      unsigned short* __restrict__ xb_next,
                                                      unsigned short* __restrict__ partO,
                                                      float* __restrict__ partM,
                                                      float* __restrict__ partL,
                                                      int split) {
    __shared__ unsigned short Klds[2][32 * 256];   // 32 KB dbuf, XOR-swizzled rows
    __shared__ unsigned short Vlds[32 * 256];      // 16 KB single, chunk-major
    __shared__ unsigned int   Plds[4][256];        // 4 KB per-wave P patch

    int tid  = threadIdx.x;
    int lane = tid & 63, wid = tid >> 6;
    int c = lane & 15, g = lane >> 4;

    // decode: XCD pair (d&7) serves batch (d&7)>>1; quads descend (LPT backfill)
    int d  = blockIdx.x;
    int b  = (d & 7) >> 1;
    int ls = __popc(split - 1);
    int combo = (d & 1) | ((d >> 3) << 1);
    int quad  = 63 - (combo >> ls);
    int s_idx = combo & (split - 1);

    int qtile = quad * 4 + wid;
    int q0 = qtile * 16;
    int nsteps_own = (q0 + 47) >> 5;
    int nsteps_max = (quad * 64 + 95) >> 5;
    int cnt_own = (nsteps_own > s_idx) ? (nsteps_own - s_idx + split - 1) / split : 0;
    int cnt_max = (nsteps_max > s_idx) ? (nsteps_max - s_idx + split - 1) / split : 0;

    const unsigned short* kbase = kb + (size_t)b * SEQ * DIM;
    const unsigned short* vbase = vt + (size_t)b * DIM * SEQ;

    auto STAGE_K = [&](int bf, int k0) {
        #pragma unroll
        for (int r = 0; r < 4; ++r) {
            // LDS byte L = r*4096 + tid*16 -> row k = r*8 + tid/32, slot sl = tid&31
            int k  = r * 8 + (tid >> 5);
            int sl = tid & 31;
            const unsigned short* ks = kbase + (size_t)(k0 + k) * DIM + ((sl ^ (k & 7)) << 3);
            gload_lds16(ks, (char*)&Klds[bf][0] + r * 4096 + wid * 1024);
        }
    };
    auto STAGE_V = [&](int k0) {
        #pragma unroll
        for (int r = 0; r < 4; ++r) {
            // LDS byte L = r*4096 + tid*16 -> chunk = r, d = tid
            const unsigned short* vs = vbase + (size_t)tid * SEQ + k0 + r * 8;
            gload_lds16(vs, (char*)&Vlds[0] + r * 4096 + wid * 1024);
        }
    };

    // hoist Q fragments (q already pre-scaled by (1/sqrt(D))*log2e)
    bf16x8 qf[8];
    const unsigned short* qp = qb + ((size_t)(b * SEQ + q0 + c)) * DIM + g * 8;
    #pragma unroll
    for (int s = 0; s < 8; ++s) qf[s] = *(const bf16x8*)(qp + s * 32);

    f32x4 o[16] = {};
    float m_run = -1e30f, l_run = 0.f;    // per-lane scalars, q = q0 + c
    int xs = ((c >> 1) & 3) << 2;         // P-patch slot rotation

    if (cnt_max > 0) {
        int kbuf = 0;
        STAGE_K(0, s_idx * KVB);

        for (int j = 0; j < cnt_max; ++j) {
            __syncthreads();   // full drain: K(j) visible to all waves; V free

            int k0 = (s_idx + j * split) * KVB;
            STAGE_V(k0);                                   // 4 loads, land during QK
            bool more = (j + 1 < cnt_max);
            if (more) STAGE_K(kbuf ^ 1, (s_idx + (j + 1) * split) * KVB);   // 4 loads

            bf16x8 paf;
            if (j < cnt_own) {
                // ---- swapped QK^T: lane holds 8 k-scores for q=q0+c ----
                f32x4 sa[2] = {};
                const unsigned short* Kb = &Klds[kbuf][0];
                __builtin_amdgcn_s_setprio(1);
                #pragma unroll
                for (int t = 0; t < 2; ++t) {
                    int krow = t * 16 + c;
                    #pragma unroll
                    for (int s = 0; s < 8; ++s) {
                        int off = krow * 256 + (((s * 4 + g) ^ (c & 7)) << 3);
                        bf16x8 kf = *(const bf16x8*)(Kb + off);
                        sa[t] = __builtin_amdgcn_mfma_f32_16x16x32_bf16(kf, qf[s], sa[t], 0, 0, 0);
                    }
                }
                __builtin_amdgcn_s_setprio(0);

                // ---- mask (edge steps only, wave-uniform branch) + row max ----
                float sv[2][4];
                float mloc = -1e30f;
                if (k0 + (KVB - 1) <= q0) {
                    #pragma unroll
                    for (int t = 0; t < 2; ++t)
                        #pragma unroll
                        for (int i = 0; i < 4; ++i) {
                            sv[t][i] = sa[t][i];
                            mloc = fmaxf(mloc, sv[t][i]);
                        }
                } else {
                    int qv = q0 + c;
                    #pragma unroll
                    for (int t = 0; t < 2; ++t)
                        #pragma unroll
                        for (int i = 0; i < 4; ++i) {
                            int key = k0 + t * 16 + g * 4 + i;
                            sv[t][i] = (key <= qv) ? sa[t][i] : -1e30f;
                            mloc = fmaxf(mloc, sv[t][i]);
                        }
                }
                mloc = fmaxf(mloc, __shfl_xor(mloc, 16));
                mloc = fmaxf(mloc, __shfl_xor(mloc, 32));

                // ---- defer-rescale (THR=8 in exp2 domain) ----
                if (!__all(mloc <= m_run + 8.0f)) {
                    float mnew = fmaxf(m_run, mloc);
                    float corr = exp2f(m_run - mnew);
                    m_run = mnew;
                    l_run *= corr;
                    #pragma unroll
                    for (int i = 0; i < 4; ++i) {
                        float cr = bperm_f(corr, g * 4 + i);
                        #pragma unroll
                        for (int dt = 0; dt < 16; ++dt) o[dt][i] *= cr;
                    }
                }

                // ---- P = exp2(S-m); pack to swizzled patch ----
                #pragma unroll
                for (int t = 0; t < 2; ++t) {
                    float p0 = exp2f(sv[t][0] - m_run);
                    float p1 = exp2f(sv[t][1] - m_run);
                    float p2 = exp2f(sv[t][2] - m_run);
                    float p3 = exp2f(sv[t][3] - m_run);
                    l_run += (p0 + p1) + (p2 + p3);
                    unsigned w0 = cvt_pk_bf16(p0, p1);
                    unsigned w1 = cvt_pk_bf16(p2, p3);
                    int s0 = (t * 8 + g * 2 + xs) & 15;    // slot(pair) = (pair+xs)&15
                    Plds[wid][c * 16 + s0]     = w0;
                    Plds[wid][c * 16 + s0 + 1] = w1;
                }
                paf = *(const bf16x8*)&Plds[wid][c * 16 + ((g * 4 + xs) & 15)];
            }

            // ---- UNIFORM: each wave drains its own V loads, then raw barrier
            //      establishes cross-wave visibility; K(j+1) stays in flight ----
            if (more) asm volatile("s_waitcnt vmcnt(4)" ::: "memory");
            else      asm volatile("s_waitcnt vmcnt(0)" ::: "memory");
            __builtin_amdgcn_s_barrier();
            __builtin_amdgcn_sched_barrier(0);

            if (j < cnt_own) {
                // ---- O += P V from LDS ----
                const unsigned short* Vb = &Vlds[0];
                __builtin_amdgcn_s_setprio(1);
                #pragma unroll
                for (int dt = 0; dt < 16; ++dt) {
                    bf16x8 vf = *(const bf16x8*)(Vb + g * 2048 + (dt * 16 + c) * 8);
                    o[dt] = __builtin_amdgcn_mfma_f32_16x16x32_bf16(paf, vf, o[dt], 0, 0, 0);
                }
                __builtin_amdgcn_s_setprio(0);
            }

            kbuf ^= 1;
        }
    }

    // ---- epilogue: reduce per-lane l partials across g-groups ----
    float lfull = l_run;
    lfull += __shfl_xor(lfull, 16);
    lfull += __shfl_xor(lfull, 32);

    if (split == 1) {
        float invl = 1.0f / lfull;
        float invr[4];
        #pragma unroll
        for (int i = 0; i < 4; ++i) invr[i] = bperm_f(invl, g * 4 + i);
        #pragma unroll
        for (int i = 0; i < 4; ++i) {
            int row = q0 + g * 4 + i;
            #pragma unroll
            for (int dt = 0; dt < 16; ++dt) {
                int col = dt * 16 + c;
                size_t idx = ((size_t)b * SEQ + row) * DIM + col;
                float r = o[dt][i] * invr[i] + xres[idx];
                xout[idx] = r;
                xb_next[idx] = f2bf(r);
            }
        }
    } else {
        int gq = b * QT + qtile;
        size_t pbase = ((size_t)(s_idx * PB + gq)) * 16;
        if (g == 0) {
            partM[pbase + c] = m_run;
            partL[pbase + c] = lfull;
        }
        #pragma unroll
        for (int i = 0; i < 4; ++i) {
            int row_r = g * 4 + i;
            #pragma unroll
            for (int dt = 0; dt < 16; ++dt) {
                partO[(pbase + row_r) * DIM + dt * 16 + c] = f2bf(o[dt][i]);
            }
        }
    }
}

// ---------------- split-KV combine + residual (partO in bf16) ----------------
__global__ __launch_bounds__(256) void combine_kernel(const unsigned short* __restrict__ partO,
                                                      const float* __restrict__ partM,
                                                      const float* __restrict__ partL,
                                                      const float* __restrict__ xres,
                                                      float* __restrict__ xout,
                                                      unsigned short* __restrict__ xb_next,
                                                      int split) {
    int q = blockIdx.x, b = blockIdx.y;
    int gq = b * QT + q;
    int t = threadIdx.x;
    int row = t >> 4, ci = t & 15;

    float mv[4];
    float M = -1e30f;
    for (int s = 0; s < split; ++s) {
        mv[s] = partM[((size_t)(s * PB + gq)) * 16 + row];
        M = fmaxf(M, mv[s]);
    }
    float L = 0.f;
    for (int s = 0; s < split; ++s)
        L += partL[((size_t)(s * PB + gq)) * 16 + row] * exp2f(mv[s] - M);
    float invL = 1.0f / L;

    float acc[16] = {};
    for (int s = 0; s < split; ++s) {
        float w = exp2f(mv[s] - M);
        if (w > 0.f) {
            const unsigned short* po = partO + (((size_t)(s * PB + gq)) * 16 + row) * DIM + ci * 16;
            #pragma unroll
            for (int j = 0; j < 4; ++j) {
                ushort4 v = *(const ushort4*)(po + j * 4);
                acc[j * 4 + 0] += w * bf2f(v.x);
                acc[j * 4 + 1] += w * bf2f(v.y);
                acc[j * 4 + 2] += w * bf2f(v.z);
                acc[j * 4 + 3] += w * bf2f(v.w);
            }
        }
    }

    size_t base = ((size_t)(b * SEQ + q * 16 + row)) * DIM + ci * 16;
    #pragma unroll
    for (int j = 0; j < 4; ++j) {
        float4 r = *(const float4*)(xres + base + j * 4);
        float4 ov;
        ov.x = acc[j * 4 + 0] * invL + r.x;
        ov.y = acc[j * 4 + 1] * invL + r.y;
        ov.z = acc[j * 4 + 2] * invL + r.z;
        ov.w = acc[j * 4 + 3] * invL + r.w;
        *(float4*)(xout + base + j * 4) = ov;
        ushort4 hb = {f2bf(ov.x), f2bf(ov.y), f2bf(ov.z), f2bf(ov.w)};
        *(ushort4*)(xb_next + base + j * 4) = hb;
    }
}

// ---------------- launch ----------------
extern "C" void kernel_launch(void* const* d_in, const int* in_sizes, int n_in,
                              void* d_out, int out_size, void* d_ws, size_t ws_size,
                              hipStream_t stream) {
    const float* x_in = (const float*)d_in[0];
    const float* Wq   = (const float*)d_in[1];
    const float* bq   = (const float*)d_in[2];
    const float* Wk   = (const float*)d_in[3];
    const float* bk   = (const float*)d_in[4];
    const float* Wv   = (const float*)d_in[5];
    const float* bv   = (const float*)d_in[6];
    float* xout = (float*)d_out;

    const size_t SD = (size_t)BATCH * SEQ * DIM;
    const size_t WL = (size_t)LAYERS * DIM * DIM;
    unsigned short* qb  = (unsigned short*)d_ws;
    unsigned short* kbf = qb  + SD;
    unsigned short* vt  = kbf + SD;
    unsigned short* xb  = vt  + SD;
    unsigned short* Wqb = xb  + SD;
    unsigned short* Wkb = Wqb + WL;
    unsigned short* Wvb = Wkb + WL;
    size_t base_bytes = (4 * SD + 3 * WL) * sizeof(unsigned short);   // ~35.1 MB

    // bf16 partO: need = split * PB*16 * (DIM*2B + 8B for M/L)
    int split = 1;
    for (int s = 4; s >= 2; s >>= 1) {
        size_t need = base_bytes + (size_t)s * PB * 16 * (DIM * 2 + 8);
        if (ws_size >= need) { split = s; break; }
    }
    unsigned short* partO = (unsigned short*)((char*)d_ws + base_bytes);
    float* partM = (float*)(partO + (size_t)split * PB * 16 * DIM);
    float* partL = partM + (size_t)split * PB * 16;

    {
        int n = (int)WL;
        int blocks = (n / 4 + 255) / 256;
        cvt_kernel<<<blocks, 256, 0, stream>>>(Wq, Wqb, n);
        cvt_kernel<<<blocks, 256, 0, stream>>>(Wk, Wkb, n);
        cvt_kernel<<<blocks, 256, 0, stream>>>(Wv, Wvb, n);
    }
    {
        int n = (int)SD;
        int blocks = (n / 4 + 255) / 256;
        cvt_kernel<<<blocks, 256, 0, stream>>>(x_in, xb, n);
    }

    dim3 pgrid(BATCH * SEQ / 64, DIM / 64), pblk(256);
    dim3 agrid(256 * split), ablk(256);
    dim3 cgrid(QT, BATCH), cblk(256);

    for (int l = 0; l < LAYERS; ++l) {
        const float* xcur = (l == 0) ? x_in : xout;
        size_t wl_off = (size_t)l * DIM * DIM;
        projqkv_kernel<<<pgrid, pblk, 0, stream>>>(xb, Wqb + wl_off, Wkb + wl_off, Wvb + wl_off,
                                                   bq + l * DIM, bk + l * DIM, bv + l * DIM,
                                                   qb, kbf, vt);
        attn_kernel<<<agrid, ablk, 0, stream>>>(qb, kbf, vt, xcur, xout, xb,
                                                partO, partM, partL, split);
        if (split > 1)
            combine_kernel<<<cgrid, cblk, 0, stream>>>(partO, partM, partL, xcur, xout, xb, split);
    }
}

// Round 11
// 531.361 us; speedup vs baseline: 2.4549x; 1.2462x over previous
//
#include <hip/hip_runtime.h>
#include <hip/hip_bf16.h>

#define SEQ 4096
#define DIM 256
#define BATCH 4
#define LAYERS 4
#define QT (SEQ / 16)        // 256 q-tiles per batch
#define PB (BATCH * QT)      // 1024 q-tiles total
#define KVB 32               // keys per KV step

typedef __attribute__((ext_vector_type(8))) short bf16x8;
typedef __attribute__((ext_vector_type(4))) float f32x4;

__device__ __forceinline__ unsigned short f2bf(float f) {
    union { float f; unsigned u; } v; v.f = f;
    unsigned r = v.u + 0x7fff + ((v.u >> 16) & 1);   // round-to-nearest-even
    return (unsigned short)(r >> 16);
}

__device__ __forceinline__ float bf2f(unsigned short h) {
    union { unsigned u; float f; } v; v.u = ((unsigned)h) << 16;
    return v.f;
}

__device__ __forceinline__ unsigned cvt_pk_bf16(float lo, float hi) {
    unsigned r;
    asm volatile("v_cvt_pk_bf16_f32 %0, %1, %2" : "=v"(r) : "v"(lo), "v"(hi));
    return r;
}

__device__ __forceinline__ float bperm_f(float v, int srclane) {
    return __int_as_float(__builtin_amdgcn_ds_bpermute(srclane << 2, __float_as_int(v)));
}

// async global->LDS, 16B per lane; LDS dest = wave-uniform base + lane*16
__device__ __forceinline__ void gload_lds16(const void* g, void* l) {
    __builtin_amdgcn_global_load_lds(
        (const __attribute__((address_space(1))) unsigned int*)g,
        (__attribute__((address_space(3))) unsigned int*)l, 16, 0, 0);
}

// ---------------- fp32 -> bf16 conversion (vectorized) ----------------
__global__ __launch_bounds__(256) void cvt_kernel(const float* __restrict__ in,
                                                  unsigned short* __restrict__ out,
                                                  int n) {
    int i = (blockIdx.x * blockDim.x + threadIdx.x) * 4;
    if (i + 3 < n) {
        float4 v = *(const float4*)(in + i);
        ushort4 o = {f2bf(v.x), f2bf(v.y), f2bf(v.z), f2bf(v.w)};
        *(ushort4*)(out + i) = o;
    }
}

// ---------------- fused QKV projection (W staged in LDS via DMA, packed stores) ----
// Per z: DMA-stage the 64x256 W tile (row-XOR swizzled) into LDS, 32 MFMA from
// LDS, packed ushort4 stores; next z's stage issues before the epilogue so it
// overlaps the stores. x fragments load under z=0's stage.
// q/k: swapped MFMA (A=W,B=x) -> thread owns 4 consecutive out-cols.
// v:   normal MFMA -> thread owns 4 consecutive rows -> transposed vt store.
// q is pre-scaled by (1/sqrt(D))*log2(e).
__global__ __launch_bounds__(256) void projqkv_kernel(const unsigned short* __restrict__ xb,
                                                      const unsigned short* __restrict__ Wq,
                                                      const unsigned short* __restrict__ Wk,
                                                      const unsigned short* __restrict__ Wv,
                                                      const float* __restrict__ bq,
                                                      const float* __restrict__ bk,
                                                      const float* __restrict__ bv,
                                                      unsigned short* __restrict__ outq,
                                                      unsigned short* __restrict__ outk,
                                                      unsigned short* __restrict__ outv) {
    __shared__ unsigned short Wlds[64 * 256];   // 32 KB

    int tid  = threadIdx.x;
    int lane = tid & 63, wid = tid >> 6;
    int c = lane & 15, g = lane >> 4;
    int m0 = blockIdx.x * 64 + wid * 16;
    int n0 = blockIdx.y * 64;

    auto STAGE_W = [&](const unsigned short* Wb) {
        #pragma unroll
        for (int r = 0; r < 8; ++r) {
            // LDS byte L = r*4096 + tid*16 -> row = r*8 + tid/32, slot sl = tid&31
            int row = r * 8 + (tid >> 5);
            int sl  = tid & 31;
            const unsigned short* ws = Wb + (size_t)(n0 + row) * DIM + ((sl ^ (row & 7)) << 3);
            gload_lds16(ws, (char*)&Wlds[0] + r * 4096 + wid * 1024);
        }
    };

    STAGE_W(Wq);   // 8 DMA loads in flight while x frags load below

    bf16x8 xa[8];
    const unsigned short* xrow = xb + (size_t)(m0 + c) * DIM + g * 8;
    #pragma unroll
    for (int s = 0; s < 8; ++s) xa[s] = *(const bf16x8*)(xrow + s * 32);

    const float KQ = 0.09016844f;   // (1/16) * log2(e)

    #pragma unroll
    for (int z = 0; z < 3; ++z) {
        __syncthreads();   // W stage drained, visible to all waves

        f32x4 acc[4] = {};
        __builtin_amdgcn_s_setprio(1);
        #pragma unroll
        for (int s = 0; s < 8; ++s) {
            #pragma unroll
            for (int nt = 0; nt < 4; ++nt) {
                int row = nt * 16 + c;
                bf16x8 wf = *(const bf16x8*)(&Wlds[0] + row * 256 + (((s * 4 + g) ^ (c & 7)) << 3));
                acc[nt] = (z == 2)
                    ? __builtin_amdgcn_mfma_f32_16x16x32_bf16(xa[s], wf, acc[nt], 0, 0, 0)
                    : __builtin_amdgcn_mfma_f32_16x16x32_bf16(wf, xa[s], acc[nt], 0, 0, 0);
            }
        }
        __builtin_amdgcn_s_setprio(0);

        __syncthreads();   // all waves done reading Wlds
        if (z == 0)      STAGE_W(Wk);   // overlap next stage with epilogue stores
        else if (z == 1) STAGE_W(Wv);

        if (z < 2) {
            const float* bias   = z ? bk : bq;
            unsigned short* out = z ? outk : outq;
            float scale = z ? 1.0f : KQ;
            #pragma unroll
            for (int nt = 0; nt < 4; ++nt) {
                int col0 = n0 + nt * 16 + g * 4;
                float4 b4 = *(const float4*)(bias + col0);
                ushort4 h = {f2bf((acc[nt][0] + b4.x) * scale),
                             f2bf((acc[nt][1] + b4.y) * scale),
                             f2bf((acc[nt][2] + b4.z) * scale),
                             f2bf((acc[nt][3] + b4.w) * scale)};
                *(ushort4*)(out + (size_t)(m0 + c) * DIM + col0) = h;
            }
        } else {
            int b    = m0 >> 12;
            int sidx = (m0 & (SEQ - 1)) + g * 4;
            #pragma unroll
            for (int nt = 0; nt < 4; ++nt) {
                int col = n0 + nt * 16 + c;
                float bv_ = bv[col];
                ushort4 h = {f2bf(acc[nt][0] + bv_), f2bf(acc[nt][1] + bv_),
                             f2bf(acc[nt][2] + bv_), f2bf(acc[nt][3] + bv_)};
                *(ushort4*)(outv + (((size_t)(b * DIM + col)) << 12) + sidx) = h;
            }
        }
    }
}

// ---------------- causal flash attention (UNCHANGED from round 10) ----------------
// K double-buffered (32KB) + V single-buffered (16KB) + P (4KB) = 52.9KB
// -> 3 blocks/CU. Per step: full barrier -> stage V(j)+K(j+1) -> QK+softmax ->
// {per-wave counted vmcnt + RAW s_barrier} (cross-wave V visibility; K(j+1)
// stays in flight) -> PV.
__global__ __launch_bounds__(256, 3) void attn_kernel(const unsigned short* __restrict__ qb,
                                                      const unsigned short* __restrict__ kb,
                                                      const unsigned short* __restrict__ vt,
                                                      const float* __restrict__ xres,
                                                      float* __restrict__ xout,
                                                      unsigned short* __restrict__ xb_next,
                                                      unsigned short* __restrict__ partO,
                                                      float* __restrict__ partM,
                                                      float* __restrict__ partL,
                                                      int split) {
    __shared__ unsigned short Klds[2][32 * 256];   // 32 KB dbuf, XOR-swizzled rows
    __shared__ unsigned short Vlds[32 * 256];      // 16 KB single, chunk-major
    __shared__ unsigned int   Plds[4][256];        // 4 KB per-wave P patch

    int tid  = threadIdx.x;
    int lane = tid & 63, wid = tid >> 6;
    int c = lane & 15, g = lane >> 4;

    // decode: XCD pair (d&7) serves batch (d&7)>>1; quads descend (LPT backfill)
    int d  = blockIdx.x;
    int b  = (d & 7) >> 1;
    int ls = __popc(split - 1);
    int combo = (d & 1) | ((d >> 3) << 1);
    int quad  = 63 - (combo >> ls);
    int s_idx = combo & (split - 1);

    int qtile = quad * 4 + wid;
    int q0 = qtile * 16;
    int nsteps_own = (q0 + 47) >> 5;
    int nsteps_max = (quad * 64 + 95) >> 5;
    int cnt_own = (nsteps_own > s_idx) ? (nsteps_own - s_idx + split - 1) / split : 0;
    int cnt_max = (nsteps_max > s_idx) ? (nsteps_max - s_idx + split - 1) / split : 0;

    const unsigned short* kbase = kb + (size_t)b * SEQ * DIM;
    const unsigned short* vbase = vt + (size_t)b * DIM * SEQ;

    auto STAGE_K = [&](int bf, int k0) {
        #pragma unroll
        for (int r = 0; r < 4; ++r) {
            int k  = r * 8 + (tid >> 5);
            int sl = tid & 31;
            const unsigned short* ks = kbase + (size_t)(k0 + k) * DIM + ((sl ^ (k & 7)) << 3);
            gload_lds16(ks, (char*)&Klds[bf][0] + r * 4096 + wid * 1024);
        }
    };
    auto STAGE_V = [&](int k0) {
        #pragma unroll
        for (int r = 0; r < 4; ++r) {
            const unsigned short* vs = vbase + (size_t)tid * SEQ + k0 + r * 8;
            gload_lds16(vs, (char*)&Vlds[0] + r * 4096 + wid * 1024);
        }
    };

    // hoist Q fragments (q already pre-scaled by (1/sqrt(D))*log2e)
    bf16x8 qf[8];
    const unsigned short* qp = qb + ((size_t)(b * SEQ + q0 + c)) * DIM + g * 8;
    #pragma unroll
    for (int s = 0; s < 8; ++s) qf[s] = *(const bf16x8*)(qp + s * 32);

    f32x4 o[16] = {};
    float m_run = -1e30f, l_run = 0.f;    // per-lane scalars, q = q0 + c
    int xs = ((c >> 1) & 3) << 2;         // P-patch slot rotation

    if (cnt_max > 0) {
        int kbuf = 0;
        STAGE_K(0, s_idx * KVB);

        for (int j = 0; j < cnt_max; ++j) {
            __syncthreads();   // full drain: K(j) visible to all waves; V free

            int k0 = (s_idx + j * split) * KVB;
            STAGE_V(k0);                                   // 4 loads, land during QK
            bool more = (j + 1 < cnt_max);
            if (more) STAGE_K(kbuf ^ 1, (s_idx + (j + 1) * split) * KVB);   // 4 loads

            bf16x8 paf;
            if (j < cnt_own) {
                // ---- swapped QK^T: lane holds 8 k-scores for q=q0+c ----
                f32x4 sa[2] = {};
                const unsigned short* Kb = &Klds[kbuf][0];
                __builtin_amdgcn_s_setprio(1);
                #pragma unroll
                for (int t = 0; t < 2; ++t) {
                    int krow = t * 16 + c;
                    #pragma unroll
                    for (int s = 0; s < 8; ++s) {
                        int off = krow * 256 + (((s * 4 + g) ^ (c & 7)) << 3);
                        bf16x8 kf = *(const bf16x8*)(Kb + off);
                        sa[t] = __builtin_amdgcn_mfma_f32_16x16x32_bf16(kf, qf[s], sa[t], 0, 0, 0);
                    }
                }
                __builtin_amdgcn_s_setprio(0);

                // ---- mask (edge steps only, wave-uniform branch) + row max ----
                float sv[2][4];
                float mloc = -1e30f;
                if (k0 + (KVB - 1) <= q0) {
                    #pragma unroll
                    for (int t = 0; t < 2; ++t)
                        #pragma unroll
                        for (int i = 0; i < 4; ++i) {
                            sv[t][i] = sa[t][i];
                            mloc = fmaxf(mloc, sv[t][i]);
                        }
                } else {
                    int qv = q0 + c;
                    #pragma unroll
                    for (int t = 0; t < 2; ++t)
                        #pragma unroll
                        for (int i = 0; i < 4; ++i) {
                            int key = k0 + t * 16 + g * 4 + i;
                            sv[t][i] = (key <= qv) ? sa[t][i] : -1e30f;
                            mloc = fmaxf(mloc, sv[t][i]);
                        }
                }
                mloc = fmaxf(mloc, __shfl_xor(mloc, 16));
                mloc = fmaxf(mloc, __shfl_xor(mloc, 32));

                // ---- defer-rescale (THR=8 in exp2 domain) ----
                if (!__all(mloc <= m_run + 8.0f)) {
                    float mnew = fmaxf(m_run, mloc);
                    float corr = exp2f(m_run - mnew);
                    m_run = mnew;
                    l_run *= corr;
                    #pragma unroll
                    for (int i = 0; i < 4; ++i) {
                        float cr = bperm_f(corr, g * 4 + i);
                        #pragma unroll
                        for (int dt = 0; dt < 16; ++dt) o[dt][i] *= cr;
                    }
                }

                // ---- P = exp2(S-m); pack to swizzled patch ----
                #pragma unroll
                for (int t = 0; t < 2; ++t) {
                    float p0 = exp2f(sv[t][0] - m_run);
                    float p1 = exp2f(sv[t][1] - m_run);
                    float p2 = exp2f(sv[t][2] - m_run);
                    float p3 = exp2f(sv[t][3] - m_run);
                    l_run += (p0 + p1) + (p2 + p3);
                    unsigned w0 = cvt_pk_bf16(p0, p1);
                    unsigned w1 = cvt_pk_bf16(p2, p3);
                    int s0 = (t * 8 + g * 2 + xs) & 15;    // slot(pair) = (pair+xs)&15
                    Plds[wid][c * 16 + s0]     = w0;
                    Plds[wid][c * 16 + s0 + 1] = w1;
                }
                paf = *(const bf16x8*)&Plds[wid][c * 16 + ((g * 4 + xs) & 15)];
            }

            // ---- UNIFORM: each wave drains its own V loads, then raw barrier
            //      establishes cross-wave visibility; K(j+1) stays in flight ----
            if (more) asm volatile("s_waitcnt vmcnt(4)" ::: "memory");
            else      asm volatile("s_waitcnt vmcnt(0)" ::: "memory");
            __builtin_amdgcn_s_barrier();
            __builtin_amdgcn_sched_barrier(0);

            if (j < cnt_own) {
                // ---- O += P V from LDS ----
                const unsigned short* Vb = &Vlds[0];
                __builtin_amdgcn_s_setprio(1);
                #pragma unroll
                for (int dt = 0; dt < 16; ++dt) {
                    bf16x8 vf = *(const bf16x8*)(Vb + g * 2048 + (dt * 16 + c) * 8);
                    o[dt] = __builtin_amdgcn_mfma_f32_16x16x32_bf16(paf, vf, o[dt], 0, 0, 0);
                }
                __builtin_amdgcn_s_setprio(0);
            }

            kbuf ^= 1;
        }
    }

    // ---- epilogue: reduce per-lane l partials across g-groups ----
    float lfull = l_run;
    lfull += __shfl_xor(lfull, 16);
    lfull += __shfl_xor(lfull, 32);

    if (split == 1) {
        float invl = 1.0f / lfull;
        float invr[4];
        #pragma unroll
        for (int i = 0; i < 4; ++i) invr[i] = bperm_f(invl, g * 4 + i);
        #pragma unroll
        for (int i = 0; i < 4; ++i) {
            int row = q0 + g * 4 + i;
            #pragma unroll
            for (int dt = 0; dt < 16; ++dt) {
                int col = dt * 16 + c;
                size_t idx = ((size_t)b * SEQ + row) * DIM + col;
                float r = o[dt][i] * invr[i] + xres[idx];
                xout[idx] = r;
                xb_next[idx] = f2bf(r);
            }
        }
    } else {
        int gq = b * QT + qtile;
        size_t pbase = ((size_t)(s_idx * PB + gq)) * 16;
        if (g == 0) {
            partM[pbase + c] = m_run;
            partL[pbase + c] = lfull;
        }
        #pragma unroll
        for (int i = 0; i < 4; ++i) {
            int row_r = g * 4 + i;
            #pragma unroll
            for (int dt = 0; dt < 16; ++dt) {
                partO[(pbase + row_r) * DIM + dt * 16 + c] = f2bf(o[dt][i]);
            }
        }
    }
}

// ---------------- split-KV combine + residual (partO in bf16) ----------------
__global__ __launch_bounds__(256) void combine_kernel(const unsigned short* __restrict__ partO,
                                                      const float* __restrict__ partM,
                                                      const float* __restrict__ partL,
                                                      const float* __restrict__ xres,
                                                      float* __restrict__ xout,
                                                      unsigned short* __restrict__ xb_next,
                                                      int split) {
    int q = blockIdx.x, b = blockIdx.y;
    int gq = b * QT + q;
    int t = threadIdx.x;
    int row = t >> 4, ci = t & 15;

    float mv[4];
    float M = -1e30f;
    for (int s = 0; s < split; ++s) {
        mv[s] = partM[((size_t)(s * PB + gq)) * 16 + row];
        M = fmaxf(M, mv[s]);
    }
    float L = 0.f;
    for (int s = 0; s < split; ++s)
        L += partL[((size_t)(s * PB + gq)) * 16 + row] * exp2f(mv[s] - M);
    float invL = 1.0f / L;

    float acc[16] = {};
    for (int s = 0; s < split; ++s) {
        float w = exp2f(mv[s] - M);
        if (w > 0.f) {
            const unsigned short* po = partO + (((size_t)(s * PB + gq)) * 16 + row) * DIM + ci * 16;
            #pragma unroll
            for (int j = 0; j < 4; ++j) {
                ushort4 v = *(const ushort4*)(po + j * 4);
                acc[j * 4 + 0] += w * bf2f(v.x);
                acc[j * 4 + 1] += w * bf2f(v.y);
                acc[j * 4 + 2] += w * bf2f(v.z);
                acc[j * 4 + 3] += w * bf2f(v.w);
            }
        }
    }

    size_t base = ((size_t)(b * SEQ + q * 16 + row)) * DIM + ci * 16;
    #pragma unroll
    for (int j = 0; j < 4; ++j) {
        float4 r = *(const float4*)(xres + base + j * 4);
        float4 ov;
        ov.x = acc[j * 4 + 0] * invL + r.x;
        ov.y = acc[j * 4 + 1] * invL + r.y;
        ov.z = acc[j * 4 + 2] * invL + r.z;
        ov.w = acc[j * 4 + 3] * invL + r.w;
        *(float4*)(xout + base + j * 4) = ov;
        ushort4 hb = {f2bf(ov.x), f2bf(ov.y), f2bf(ov.z), f2bf(ov.w)};
        *(ushort4*)(xb_next + base + j * 4) = hb;
    }
}

// ---------------- launch ----------------
extern "C" void kernel_launch(void* const* d_in, const int* in_sizes, int n_in,
                              void* d_out, int out_size, void* d_ws, size_t ws_size,
                              hipStream_t stream) {
    const float* x_in = (const float*)d_in[0];
    const float* Wq   = (const float*)d_in[1];
    const float* bq   = (const float*)d_in[2];
    const float* Wk   = (const float*)d_in[3];
    const float* bk   = (const float*)d_in[4];
    const float* Wv   = (const float*)d_in[5];
    const float* bv   = (const float*)d_in[6];
    float* xout = (float*)d_out;

    const size_t SD = (size_t)BATCH * SEQ * DIM;
    const size_t WL = (size_t)LAYERS * DIM * DIM;
    unsigned short* qb  = (unsigned short*)d_ws;
    unsigned short* kbf = qb  + SD;
    unsigned short* vt  = kbf + SD;
    unsigned short* xb  = vt  + SD;
    unsigned short* Wqb = xb  + SD;
    unsigned short* Wkb = Wqb + WL;
    unsigned short* Wvb = Wkb + WL;
    size_t base_bytes = (4 * SD + 3 * WL) * sizeof(unsigned short);   // ~35.1 MB

    // bf16 partO: need = split * PB*16 * (DIM*2B + 8B for M/L)
    int split = 1;
    for (int s = 4; s >= 2; s >>= 1) {
        size_t need = base_bytes + (size_t)s * PB * 16 * (DIM * 2 + 8);
        if (ws_size >= need) { split = s; break; }
    }
    unsigned short* partO = (unsigned short*)((char*)d_ws + base_bytes);
    float* partM = (float*)(partO + (size_t)split * PB * 16 * DIM);
    float* partL = partM + (size_t)split * PB * 16;

    {
        int n = (int)WL;
        int blocks = (n / 4 + 255) / 256;
        cvt_kernel<<<blocks, 256, 0, stream>>>(Wq, Wqb, n);
        cvt_kernel<<<blocks, 256, 0, stream>>>(Wk, Wkb, n);
        cvt_kernel<<<blocks, 256, 0, stream>>>(Wv, Wvb, n);
    }
    {
        int n = (int)SD;
        int blocks = (n / 4 + 255) / 256;
        cvt_kernel<<<blocks, 256, 0, stream>>>(x_in, xb, n);
    }

    dim3 pgrid(BATCH * SEQ / 64, DIM / 64), pblk(256);
    dim3 agrid(256 * split), ablk(256);
    dim3 cgrid(QT, BATCH), cblk(256);

    for (int l = 0; l < LAYERS; ++l) {
        const float* xcur = (l == 0) ? x_in : xout;
        size_t wl_off = (size_t)l * DIM * DIM;
        projqkv_kernel<<<pgrid, pblk, 0, stream>>>(xb, Wqb + wl_off, Wkb + wl_off, Wvb + wl_off,
                                                   bq + l * DIM, bk + l * DIM, bv + l * DIM,
                                                   qb, kbf, vt);
        attn_kernel<<<agrid, ablk, 0, stream>>>(qb, kbf, vt, xcur, xout, xb,
                                                partO, partM, partL, split);
        if (split > 1)
            combine_kernel<<<cgrid, cblk, 0, stream>>>(partO, partM, partL, xcur, xout, xb, split);
    }
}